// Round 11
// baseline (385.103 us; speedup 1.0000x reference)
//
#include <hip/hip_runtime.h>
#include <stdint.h>

#define BB 4
#define LL 16384
#define CC 512
#define MM (BB * LL)  // 65536

typedef unsigned short u16;
typedef __bf16 bf16x8 __attribute__((ext_vector_type(8)));
typedef float f32x4 __attribute__((ext_vector_type(4)));
typedef u16 u16x8 __attribute__((ext_vector_type(8)));
typedef u16 u16x4 __attribute__((ext_vector_type(4)));

__device__ __forceinline__ u16 f2bf(float f) {
  return __builtin_bit_cast(u16, (__bf16)f);
}

__device__ __forceinline__ void gl_lds16(const void* g, void* l) {
  __builtin_amdgcn_global_load_lds((const __attribute__((address_space(1))) void*)g,
                                   (__attribute__((address_space(3))) void*)l,
                                   16, 0, 0);
}

// ---------------- fused prep: fp32->bf16 cvt (q,kv) + weight transpose-cvt ----------
// q/kv fp32 reads are nontemporal (read-once; don't evict qp/kvp from L3).
__global__ __launch_bounds__(256) void prep_kernel(
    const float* __restrict__ q, const float* __restrict__ kv,
    const float* __restrict__ Wq, const float* __restrict__ Wkv,
    const float* __restrict__ Wfc, u16* __restrict__ qo, u16* __restrict__ kvo,
    u16* __restrict__ Wq_t, u16* __restrict__ Wkv_t, u16* __restrict__ Wfc_t) {
  __shared__ float tile[64][65];
  const int bid = blockIdx.x, tid = threadIdx.x;

  if (bid < 4096) {
    const int half = bid >> 11;
    const float* src = half ? kv : q;
    u16* dst = half ? kvo : qo;
    const int n16 = MM * CC / 16;  // 2097152
    const int stride = 2048 * 256;
    for (int i = (bid & 2047) * 256 + tid; i < n16; i += stride) {
      const f32x4* sp = reinterpret_cast<const f32x4*>(src) + 4 * i;
      f32x4 a0 = __builtin_nontemporal_load(sp + 0);
      f32x4 a1 = __builtin_nontemporal_load(sp + 1);
      f32x4 a2 = __builtin_nontemporal_load(sp + 2);
      f32x4 a3 = __builtin_nontemporal_load(sp + 3);
      u16x8 o0, o1;
      o0[0] = f2bf(a0[0]); o0[1] = f2bf(a0[1]); o0[2] = f2bf(a0[2]); o0[3] = f2bf(a0[3]);
      o0[4] = f2bf(a1[0]); o0[5] = f2bf(a1[1]); o0[6] = f2bf(a1[2]); o0[7] = f2bf(a1[3]);
      o1[0] = f2bf(a2[0]); o1[1] = f2bf(a2[1]); o1[2] = f2bf(a2[2]); o1[3] = f2bf(a2[3]);
      o1[4] = f2bf(a3[0]); o1[5] = f2bf(a3[1]); o1[6] = f2bf(a3[2]); o1[7] = f2bf(a3[3]);
      reinterpret_cast<u16x8*>(dst)[2 * i + 0] = o0;
      reinterpret_cast<u16x8*>(dst)[2 * i + 1] = o1;
    }
    return;
  }

  // weight transpose: W[K][N] -> Wt[N][K] bf16, 64x64 tiles
  const int wb = bid - 4096;
  const float* W; u16* Wt; int N, ti;
  if (wb < 64)       { W = Wq;  Wt = Wq_t;  N = 512;  ti = wb; }
  else if (wb < 192) { W = Wkv; Wt = Wkv_t; N = 1024; ti = wb - 64; }
  else               { W = Wfc; Wt = Wfc_t; N = 512;  ti = wb - 192; }
  const int ntn = N >> 6;
  const int kt = ti / ntn, nt = ti % ntn;
  const int k0 = kt << 6, n0 = nt << 6;
  {
    const int r = tid >> 4, c4 = tid & 15;
#pragma unroll
    for (int e = 0; e < 4; ++e) {
      int row = r + e * 16;
      f32x4 v = *reinterpret_cast<const f32x4*>(&W[(size_t)(k0 + row) * N + n0 + c4 * 4]);
      tile[row][c4 * 4 + 0] = v[0]; tile[row][c4 * 4 + 1] = v[1];
      tile[row][c4 * 4 + 2] = v[2]; tile[row][c4 * 4 + 3] = v[3];
    }
  }
  __syncthreads();
  {
    const int n = tid >> 2, qd = tid & 3;
#pragma unroll
    for (int e = 0; e < 2; ++e) {
      int c = qd * 2 + e;
      u16x8 o;
#pragma unroll
      for (int j = 0; j < 8; ++j) o[j] = f2bf(tile[c * 8 + j][n]);
      *reinterpret_cast<u16x8*>(&Wt[(size_t)(n0 + n) * 512 + k0 + c * 8]) = o;
    }
  }
}

// ------------- persistent 256x256 8-phase NT GEMM: C = A[M][512] * Bt[N][512]^T -----
// Grid = 256 blocks (1/CU, XCD-swizzled); each block owns TPB consecutive output
// tiles (same A panel -> L2 reuse). K=512 fixed -> NT=8 K-tiles per output tile.
// The staging stream is CONTINUOUS across output tiles (flat tau counter):
// tile tau reads A[cur]/B[cur]; stages tile tau+2 (p1: Ah0->Asta, p2: Ah1->Asta
// + Bh0->Bcur, p3: Bh1->Bcur); end-of-tile vmcnt(8) drains the loads staged at
// tau-1 (needed at tau+1), leaving this tile's 8 in flight. A rotates mod 3,
// B mod 2 -- invariants identical at output-tile boundaries (addresses jump).
// C-write for tile T is issued after T's last barrier and overlaps (T+1,0)'s
// compute; the following drain waits on those stores with a K-tile of cover.
template <bool OUT_F32>
__global__ __launch_bounds__(512, 2) void gemm256(const u16* __restrict__ A,
                                                  const u16* __restrict__ Bt,
                                                  void* __restrict__ Cp,
                                                  int N, int TPB, int nbnl) {
  constexpr int K = 512;
  constexpr int NT = 8;
  __shared__ __align__(16) u16 Al[3][16384];
  __shared__ __align__(16) u16 Bl[2][16384];
  const int bid0 = blockIdx.x;
  const int bid = (bid0 & 7) * 32 + (bid0 >> 3);  // 256 blocks, XCD swizzle
  const int T0 = bid * TPB;
  const int taumax = TPB * NT;
  const int tid = threadIdx.x, lane = tid & 63;
  const int wv = tid >> 6, wm = wv >> 2, wn = wv & 3;
  const int ro = lane & 15, g4 = lane >> 4;

  // staging geometry: chunk ci = (row r = ci>>3, colgroup g = ci&7) of a 128x64
  // half-tile. LDS dest LINEAR; global source colgroup pre-swizzled g^(r&7).
  const int ci0 = tid, ci1 = tid + 512;
  const int r0 = ci0 >> 3, g0 = (ci0 & 7) ^ (r0 & 7);
  const int r1 = ci1 >> 3, g1 = (ci1 & 7) ^ (r1 & 7);

  auto stageA = [&](int half, size_t row0s, int us, u16* L) {
    gl_lds16(A + (row0s + half * 128 + r0) * (size_t)K + us * 64 + g0 * 8, L + half * 8192 + ci0 * 8);
    gl_lds16(A + (row0s + half * 128 + r1) * (size_t)K + us * 64 + g1 * 8, L + half * 8192 + ci1 * 8);
  };
  auto stageB = [&](int half, size_t col0s, int us, u16* L) {
    gl_lds16(Bt + (col0s + half * 128 + r0) * (size_t)K + us * 64 + g0 * 8, L + half * 8192 + ci0 * 8);
    gl_lds16(Bt + (col0s + half * 128 + r1) * (size_t)K + us * 64 + g1 * 8, L + half * 8192 + ci1 * 8);
  };

  // ds_read offsets (u16 elems), swizzled: phys colgroup = logical ^ (row&7)
  const int aB = (wm * 128 + ro) * 64;
  const int bB = (wn * 64 + ro) * 64;
  const int sw0 = (g4 ^ (ro & 7)) * 8;
  const int sw1 = ((g4 + 4) ^ (ro & 7)) * 8;

  auto ldf = [&](const u16* p) { return *reinterpret_cast<const bf16x8*>(p); };
  auto trow = [&](int T) { return (size_t)(T >> nbnl) << 8; };
  auto tcol = [&](int T) { return (size_t)(T & ((1 << nbnl) - 1)) << 8; };

  f32x4 acc[8][4] = {};

  // prologue: stage tau=0,1 (both in T0 since NT=8); drain tile 0 (leave 8 in flight)
  {
    size_t sr = trow(T0), sc = tcol(T0);
    stageA(0, sr, 0, Al[0]); stageA(1, sr, 0, Al[0]);
    stageB(0, sc, 0, Bl[0]); stageB(1, sc, 0, Bl[0]);
    stageA(0, sr, 1, Al[1]); stageA(1, sr, 1, Al[1]);
    stageB(0, sc, 1, Bl[1]); stageB(1, sc, 1, Bl[1]);
  }
  asm volatile("s_waitcnt vmcnt(8)" ::: "memory");
  __builtin_amdgcn_s_barrier();

  u16 *Acur = Al[0], *Anxt = Al[1], *Asta = Al[2];
  u16 *Bcur = Bl[0], *Bnxt = Bl[1];

  int tau = 0;
  for (int T = T0; T < T0 + TPB; ++T) {
    const size_t erow0 = trow(T), ecol0 = tcol(T);
    for (int u = 0; u < NT; ++u, ++tau) {
      const int tau2 = tau + 2;
      const bool st = tau2 < taumax;
      const int us = tau2 & 7;
      const int T2 = T0 + (tau2 >> 3);
      const size_t srow0 = trow(T2), scol0 = tcol(T2);
      bf16x8 bfr[4][2], af[2][2];

      // ---- phase 1: all B frags + A m0,m1; stage A(tau+2) h0 -> Asta ----
#pragma unroll
      for (int n = 0; n < 4; ++n) {
        bfr[n][0] = ldf(Bcur + bB + n * 1024 + sw0);
        bfr[n][1] = ldf(Bcur + bB + n * 1024 + sw1);
      }
      af[0][0] = ldf(Acur + aB + sw0);        af[0][1] = ldf(Acur + aB + sw1);
      af[1][0] = ldf(Acur + aB + 1024 + sw0); af[1][1] = ldf(Acur + aB + 1024 + sw1);
      if (st) stageA(0, srow0, us, Asta);
      __builtin_amdgcn_s_barrier();
      asm volatile("s_waitcnt lgkmcnt(0)" ::: "memory");
      __builtin_amdgcn_sched_barrier(0);
      __builtin_amdgcn_s_setprio(1);
#pragma unroll
      for (int m = 0; m < 2; ++m)
#pragma unroll
        for (int n = 0; n < 4; ++n) {
          acc[m][n] = __builtin_amdgcn_mfma_f32_16x16x32_bf16(af[m][0], bfr[n][0], acc[m][n], 0, 0, 0);
          acc[m][n] = __builtin_amdgcn_mfma_f32_16x16x32_bf16(af[m][1], bfr[n][1], acc[m][n], 0, 0, 0);
        }
      __builtin_amdgcn_s_setprio(0);
      __builtin_amdgcn_s_barrier();

      // ---- phases 2..4: A m=2ph..2ph+1; stage Ah1+Bh0 / Bh1 / - ; end: drain ----
#pragma unroll
      for (int ph = 1; ph < 4; ++ph) {
        af[0][0] = ldf(Acur + aB + (2 * ph) * 1024 + sw0);
        af[0][1] = ldf(Acur + aB + (2 * ph) * 1024 + sw1);
        af[1][0] = ldf(Acur + aB + (2 * ph + 1) * 1024 + sw0);
        af[1][1] = ldf(Acur + aB + (2 * ph + 1) * 1024 + sw1);
        if (ph == 1) { if (st) { stageA(1, srow0, us, Asta); stageB(0, scol0, us, Bcur); } }
        else if (ph == 2) { if (st) stageB(1, scol0, us, Bcur); }
        __builtin_amdgcn_s_barrier();
        asm volatile("s_waitcnt lgkmcnt(0)" ::: "memory");
        __builtin_amdgcn_sched_barrier(0);
        __builtin_amdgcn_s_setprio(1);
#pragma unroll
        for (int m = 0; m < 2; ++m)
#pragma unroll
          for (int n = 0; n < 4; ++n) {
            acc[2 * ph + m][n] =
                __builtin_amdgcn_mfma_f32_16x16x32_bf16(af[m][0], bfr[n][0], acc[2 * ph + m][n], 0, 0, 0);
            acc[2 * ph + m][n] =
                __builtin_amdgcn_mfma_f32_16x16x32_bf16(af[m][1], bfr[n][1], acc[2 * ph + m][n], 0, 0, 0);
          }
        __builtin_amdgcn_s_setprio(0);
        if (ph == 3) {
          if (st) asm volatile("s_waitcnt vmcnt(8)" ::: "memory");
          else    asm volatile("s_waitcnt vmcnt(0)" ::: "memory");
        }
        __builtin_amdgcn_s_barrier();
      }

      // rotate buffers
      u16* ta = Acur; Acur = Anxt; Anxt = Asta; Asta = ta;
      u16* tb = Bcur; Bcur = Bnxt; Bnxt = tb;
    }

    // epilogue for tile T: issue C stores (overlap next tile's compute), zero acc
#pragma unroll
    for (int m = 0; m < 8; ++m)
#pragma unroll
      for (int n = 0; n < 4; ++n) {
#pragma unroll
        for (int j = 0; j < 4; ++j) {
          size_t r = erow0 + wm * 128 + m * 16 + g4 * 4 + j;
          size_t c = ecol0 + wn * 64 + n * 16 + ro;
          if (OUT_F32)
            reinterpret_cast<float*>(Cp)[r * N + c] = acc[m][n][j];
          else
            reinterpret_cast<u16*>(Cp)[r * N + c] = f2bf(acc[m][n][j]);
        }
        acc[m][n] = (f32x4){0.f, 0.f, 0.f, 0.f};
      }
  }
}

// ---------------- window attention ----------------
// grid: b*512 + w*8 + h  (2048 blocks), 512 threads (8 waves, 32 q-rows each).
// K in LDS via global_load_lds with pre-swizzled source (32KB); V transposed in
// LDS, XOR-swizzled (32KB); P per-wave quarter-split, XOR-swizzled (16KB).
// Total exactly 80KB -> 2 blocks/CU.
__global__ __launch_bounds__(512, 4) void attn_kernel(const u16* __restrict__ qp,
                                                      const u16* __restrict__ kvp,
                                                      u16* __restrict__ o) {
  __shared__ __align__(16) u16 Kl[256 * 64];
  __shared__ __align__(16) u16 Vt[64 * 256];
  __shared__ __align__(16) u16 Pl[8 * 1024];
  const int bid = blockIdx.x;
  const int h = bid & 7, w = (bid >> 3) & 63, b = bid >> 9;
  const int w1 = w >> 3, w2 = w & 7;
  const int tid = threadIdx.x, lane = tid & 63, wv = tid >> 6;

  auto lrow = [&](int t) { return (w1 * 16 + (t >> 4)) * 128 + w2 * 16 + (t & 15); };

  // stage K: 2048 16B chunks; LDS dest linear; global source pre-swizzled g^(r&7).
#pragma unroll
  for (int p = 0; p < 4; ++p) {
    int ci = tid + p * 512;
    int r = ci >> 3, g = (ci & 7) ^ (r & 7);
    gl_lds16(kvp + ((size_t)(b * LL + lrow(r))) * 1024 + h * 64 + g * 8, Kl + ci * 8);
  }
  // stage V transposed, swizzled: (d, tk) at phys d*256 + ((tk>>3)^(d&7))*8 + (tk&7)
  {
    const int tk = tid >> 1, half = tid & 1;
    const size_t base = ((size_t)(b * LL + lrow(tk))) * 1024 + 512 + h * 64 + half * 32;
#pragma unroll
    for (int c = 0; c < 4; ++c) {
      u16x8 vx = *reinterpret_cast<const u16x8*>(kvp + base + c * 8);
#pragma unroll
      for (int e = 0; e < 8; ++e) {
        int d = half * 32 + c * 8 + e;
        Vt[d * 256 + (((tk >> 3) ^ (d & 7)) * 8) + (tk & 7)] = vx[e];
      }
    }
  }
  __syncthreads();

  const int ro = lane & 15;       // low nibble
  const int g4 = lane >> 4;       // lane group 0..3
  const float scale = 0.125f;     // hd^-0.5, hd=64
  const int swA = (g4 ^ (ro & 7)) * 8;
  const int swB = ((g4 + 4) ^ (ro & 7)) * 8;
  u16* PW = Pl + wv * 1024;

  auto ldf = [&](const u16* p) { return *reinterpret_cast<const bf16x8*>(p); };

#pragma unroll
  for (int rt = 0; rt < 2; ++rt) {
    // Q fragments for this 16-row tile, direct from global
    const int tq = 32 * wv + 16 * rt + ro;
    const size_t qbase = ((size_t)(b * LL + lrow(tq))) * 512 + h * 64 + g4 * 8;
    const bf16x8 qf0 = *reinterpret_cast<const bf16x8*>(qp + qbase);
    const bf16x8 qf1 = *reinterpret_cast<const bf16x8*>(qp + qbase + 32);

    // S = Q K^T : 16 q-rows x 256 keys; K frags from swizzled LDS
    f32x4 sa[16] = {};
    __builtin_amdgcn_s_setprio(1);
#pragma unroll
    for (int ct = 0; ct < 16; ++ct) {
      bf16x8 kf0 = ldf(Kl + (16 * ct + ro) * 64 + swA);
      bf16x8 kf1 = ldf(Kl + (16 * ct + ro) * 64 + swB);
      sa[ct] = __builtin_amdgcn_mfma_f32_16x16x32_bf16(qf0, kf0, sa[ct], 0, 0, 0);
      sa[ct] = __builtin_amdgcn_mfma_f32_16x16x32_bf16(qf1, kf1, sa[ct], 0, 0, 0);
    }
    __builtin_amdgcn_s_setprio(0);

    // softmax per q-row (row = g4*4 + j, key = 16*ct + ro)
#pragma unroll
    for (int j = 0; j < 4; ++j) {
      float m = -1e30f;
#pragma unroll
      for (int ct = 0; ct < 16; ++ct) m = fmaxf(m, sa[ct][j]);
      m = fmaxf(m, __shfl_xor(m, 1));
      m = fmaxf(m, __shfl_xor(m, 2));
      m = fmaxf(m, __shfl_xor(m, 4));
      m = fmaxf(m, __shfl_xor(m, 8));
      m *= scale;
      float s = 0.f;
#pragma unroll
      for (int ct = 0; ct < 16; ++ct) {
        float p = __expf(sa[ct][j] * scale - m);
        sa[ct][j] = p;
        s += p;
      }
      s += __shfl_xor(s, 1);
      s += __shfl_xor(s, 2);
      s += __shfl_xor(s, 4);
      s += __shfl_xor(s, 8);
      float inv = 1.f / s;
#pragma unroll
      for (int ct = 0; ct < 16; ++ct) sa[ct][j] *= inv;
    }

    // O = P V in four key-quarters through the per-wave swizzled LDS P tile.
    f32x4 oacc[4] = {};
#pragma unroll
    for (int kh = 0; kh < 4; ++kh) {
#pragma unroll
      for (int c = 0; c < 4; ++c)
#pragma unroll
        for (int j = 0; j < 4; ++j) {
          int rq = g4 * 4 + j;
          PW[rq * 64 + (((2 * c + (ro >> 3)) ^ (rq & 7)) * 8) + (ro & 7)] =
              f2bf(sa[kh * 4 + c][j]);
        }
      __builtin_amdgcn_s_setprio(1);
#pragma unroll
      for (int ks = 0; ks < 2; ++ks) {
        bf16x8 pf = ldf(PW + ro * 64 + (((ks * 4 + g4) ^ (ro & 7)) * 8));
        const int kkg = kh * 2 + ks;
#pragma unroll
        for (int cd = 0; cd < 4; ++cd) {
          bf16x8 vf = ldf(Vt + (16 * cd + ro) * 256 + (((kkg * 4 + g4) ^ (ro & 7)) * 8));
          oacc[cd] = __builtin_amdgcn_mfma_f32_16x16x32_bf16(pf, vf, oacc[cd], 0, 0, 0);
        }
      }
      __builtin_amdgcn_s_setprio(0);
    }

    // write out this 16-row tile
#pragma unroll
    for (int cd = 0; cd < 4; ++cd)
#pragma unroll
      for (int j = 0; j < 4; ++j) {
        int t = 32 * wv + 16 * rt + g4 * 4 + j;
        int d = 16 * cd + ro;
        o[((size_t)(b * LL + lrow(t))) * 512 + h * 64 + d] = f2bf(oacc[cd][j]);
      }
  }
}

// ---------------- launch ----------------
extern "C" void kernel_launch(void* const* d_in, const int* in_sizes, int n_in,
                              void* d_out, int out_size, void* d_ws, size_t ws_size,
                              hipStream_t stream) {
  const float* q = (const float*)d_in[0];
  const float* kv = (const float*)d_in[1];
  const float* Wq = (const float*)d_in[2];
  const float* Wkv = (const float*)d_in[3];
  const float* Wfc = (const float*)d_in[4];
  float* out = (float*)d_out;
  char* ws = (char*)d_ws;

  // workspace layout (bytes)
  u16* q_bf  = (u16*)(ws + 0);            // 67108864  (also reused as o_buf)
  u16* kv_bf = (u16*)(ws + 67108864);     // 67108864
  u16* qp    = (u16*)(ws + 134217728);    // 67108864
  u16* kvp   = (u16*)(ws + 201326592);    // 134217728
  u16* Wq_t  = (u16*)(ws + 335544320);    // 524288
  u16* Wkv_t = (u16*)(ws + 336068608);    // 1048576
  u16* Wfc_t = (u16*)(ws + 337117184);    // 524288
  u16* o_buf = q_bf;                      // q_bf dead after GEMM1

  prep_kernel<<<4352, 256, 0, stream>>>(q, kv, Wq, Wkv, Wfc, q_bf, kv_bf, Wq_t, Wkv_t, Wfc_t);

  // persistent GEMMs: grid 256, TPB tiles/block (tiles share A panel)
  gemm256<false><<<256, 512, 0, stream>>>(q_bf, Wq_t, qp, CC, 2, 1);
  gemm256<false><<<256, 512, 0, stream>>>(kv_bf, Wkv_t, kvp, 2 * CC, 4, 2);

  attn_kernel<<<BB * 64 * 8, 512, 0, stream>>>(qp, kvp, o_buf);

  gemm256<true><<<256, 512, 0, stream>>>(o_buf, Wfc_t, out, CC, 2, 1);
}

// Round 12
// 366.740 us; speedup vs baseline: 1.0501x; 1.0501x over previous
//
#include <hip/hip_runtime.h>
#include <stdint.h>

#define BB 4
#define LL 16384
#define CC 512
#define MM (BB * LL)  // 65536

typedef unsigned short u16;
typedef __bf16 bf16x8 __attribute__((ext_vector_type(8)));
typedef float f32x4 __attribute__((ext_vector_type(4)));
typedef u16 u16x8 __attribute__((ext_vector_type(8)));
typedef u16 u16x4 __attribute__((ext_vector_type(4)));

__device__ __forceinline__ u16 f2bf(float f) {
  return __builtin_bit_cast(u16, (__bf16)f);
}

__device__ __forceinline__ void gl_lds16(const void* g, void* l) {
  __builtin_amdgcn_global_load_lds((const __attribute__((address_space(1))) void*)g,
                                   (__attribute__((address_space(3))) void*)l,
                                   16, 0, 0);
}

// ---------------- fused prep: fp32->bf16 cvt (q,kv) + weight transpose-cvt ----------
__global__ __launch_bounds__(256) void prep_kernel(
    const float* __restrict__ q, const float* __restrict__ kv,
    const float* __restrict__ Wq, const float* __restrict__ Wkv,
    const float* __restrict__ Wfc, u16* __restrict__ qo, u16* __restrict__ kvo,
    u16* __restrict__ Wq_t, u16* __restrict__ Wkv_t, u16* __restrict__ Wfc_t) {
  __shared__ float tile[64][65];
  const int bid = blockIdx.x, tid = threadIdx.x;

  if (bid < 4096) {
    const int half = bid >> 11;
    const float* src = half ? kv : q;
    u16* dst = half ? kvo : qo;
    const int n16 = MM * CC / 16;  // 2097152
    const int stride = 2048 * 256;
    for (int i = (bid & 2047) * 256 + tid; i < n16; i += stride) {
      const f32x4* sp = reinterpret_cast<const f32x4*>(src) + 4 * i;
      f32x4 a0 = __builtin_nontemporal_load(sp + 0);
      f32x4 a1 = __builtin_nontemporal_load(sp + 1);
      f32x4 a2 = __builtin_nontemporal_load(sp + 2);
      f32x4 a3 = __builtin_nontemporal_load(sp + 3);
      u16x8 o0, o1;
      o0[0] = f2bf(a0[0]); o0[1] = f2bf(a0[1]); o0[2] = f2bf(a0[2]); o0[3] = f2bf(a0[3]);
      o0[4] = f2bf(a1[0]); o0[5] = f2bf(a1[1]); o0[6] = f2bf(a1[2]); o0[7] = f2bf(a1[3]);
      o1[0] = f2bf(a2[0]); o1[1] = f2bf(a2[1]); o1[2] = f2bf(a2[2]); o1[3] = f2bf(a2[3]);
      o1[4] = f2bf(a3[0]); o1[5] = f2bf(a3[1]); o1[6] = f2bf(a3[2]); o1[7] = f2bf(a3[3]);
      reinterpret_cast<u16x8*>(dst)[2 * i + 0] = o0;
      reinterpret_cast<u16x8*>(dst)[2 * i + 1] = o1;
    }
    return;
  }

  // weight transpose: W[K][N] -> Wt[N][K] bf16, 64x64 tiles
  const int wb = bid - 4096;
  const float* W; u16* Wt; int N, ti;
  if (wb < 64)       { W = Wq;  Wt = Wq_t;  N = 512;  ti = wb; }
  else if (wb < 192) { W = Wkv; Wt = Wkv_t; N = 1024; ti = wb - 64; }
  else               { W = Wfc; Wt = Wfc_t; N = 512;  ti = wb - 192; }
  const int ntn = N >> 6;
  const int kt = ti / ntn, nt = ti % ntn;
  const int k0 = kt << 6, n0 = nt << 6;
  {
    const int r = tid >> 4, c4 = tid & 15;
#pragma unroll
    for (int e = 0; e < 4; ++e) {
      int row = r + e * 16;
      f32x4 v = *reinterpret_cast<const f32x4*>(&W[(size_t)(k0 + row) * N + n0 + c4 * 4]);
      tile[row][c4 * 4 + 0] = v[0]; tile[row][c4 * 4 + 1] = v[1];
      tile[row][c4 * 4 + 2] = v[2]; tile[row][c4 * 4 + 3] = v[3];
    }
  }
  __syncthreads();
  {
    const int n = tid >> 2, qd = tid & 3;
#pragma unroll
    for (int e = 0; e < 2; ++e) {
      int c = qd * 2 + e;
      u16x8 o;
#pragma unroll
      for (int j = 0; j < 8; ++j) o[j] = f2bf(tile[c * 8 + j][n]);
      *reinterpret_cast<u16x8*>(&Wt[(size_t)(n0 + n) * 512 + k0 + c * 8]) = o;
    }
  }
}

// ---- 128x128 2-phase NT GEMM, 3 blocks/CU: C[M][N] = A[M][512] * Bt[N][512]^T ----
// 256 threads (4 waves, 2M x 2N, 64x64/wave). LDS 48KB: A double-buffer (2x16KB)
// + B single-buffer (16KB) -> 3 blocks/CU. Independent co-resident blocks
// interleave DS/MFMA/stall phases (the anti-lockstep occupancy fix).
// Race discipline: A(u+1) -> idle A buffer @p1 (that buffer's reads closed by
// tile(u-1)'s end barrier). B single-buffered: all B ds_reads of tile u are
// lgkm-drained before p1's post-MFMA barrier, so B(u+1) staging @p2 is safe.
// Tile-end vmcnt(0)+barrier publishes both staged tiles for tile u+1.
// XCD-chunked bid swizzle: same-A-panel tiles colocate on one XCD (L2 reuse).
template <bool OUT_F32>
__global__ __launch_bounds__(256, 3) void gemm128(const u16* __restrict__ A,
                                                  const u16* __restrict__ Bt,
                                                  void* __restrict__ Cp,
                                                  int N, int nbnl) {
  constexpr int K = 512;
  constexpr int NT = 8;
  __shared__ __align__(16) u16 Al[2][8192];
  __shared__ __align__(16) u16 Bl[8192];
  const int nwg = gridDim.x;
  const int bid0 = blockIdx.x;
  const int cpx = nwg >> 3;  // grids are multiples of 8
  const int bid = (bid0 & 7) * cpx + (bid0 >> 3);
  const int bm = bid >> nbnl, bn = bid & ((1 << nbnl) - 1);
  const size_t row0 = (size_t)bm << 7, col0 = (size_t)bn << 7;
  const int tid = threadIdx.x, lane = tid & 63;
  const int wv = tid >> 6, wm = wv >> 1, wn = wv & 1;
  const int ro = lane & 15, g4 = lane >> 4;

  // staging: 1024 16B chunks per 128x64 tile; chunk cc = (row r = cc>>3,
  // colgroup g = cc&7). LDS dest LINEAR; global source pre-swizzled g^(r&7).
  auto stageA = [&](int kt, u16* L) {
#pragma unroll
    for (int c = 0; c < 4; ++c) {
      int cc = tid + c * 256;
      int r = cc >> 3, g = (cc & 7) ^ (r & 7);
      gl_lds16(A + (row0 + r) * (size_t)K + kt * 64 + g * 8, L + cc * 8);
    }
  };
  auto stageB = [&](int kt) {
#pragma unroll
    for (int c = 0; c < 4; ++c) {
      int cc = tid + c * 256;
      int r = cc >> 3, g = (cc & 7) ^ (r & 7);
      gl_lds16(Bt + (col0 + r) * (size_t)K + kt * 64 + g * 8, Bl + cc * 8);
    }
  };

  // ds_read offsets (u16 elems), swizzled: phys colgroup = logical ^ (row&7)
  const int aB = (wm * 64 + ro) * 64;
  const int bB = (wn * 64 + ro) * 64;
  const int sw0 = (g4 ^ (ro & 7)) * 8;
  const int sw1 = ((g4 + 4) ^ (ro & 7)) * 8;

  auto ldf = [&](const u16* p) { return *reinterpret_cast<const bf16x8*>(p); };

  f32x4 acc[4][4] = {};

  // prologue: stage tile 0, full drain
  stageA(0, Al[0]); stageB(0);
  asm volatile("s_waitcnt vmcnt(0)" ::: "memory");
  __builtin_amdgcn_s_barrier();

  for (int u = 0; u < NT; ++u) {
    u16* LA = Al[u & 1];
    u16* LAn = Al[(u + 1) & 1];
    const bool st = (u + 1) < NT;
    bf16x8 bfr[4][2], af[2][2];

    // ---- phase 1: all B frags + A m0,m1; stage A(u+1) -> idle buffer ----
#pragma unroll
    for (int n = 0; n < 4; ++n) {
      bfr[n][0] = ldf(Bl + bB + n * 1024 + sw0);
      bfr[n][1] = ldf(Bl + bB + n * 1024 + sw1);
    }
    af[0][0] = ldf(LA + aB + sw0);        af[0][1] = ldf(LA + aB + sw1);
    af[1][0] = ldf(LA + aB + 1024 + sw0); af[1][1] = ldf(LA + aB + 1024 + sw1);
    if (st) stageA(u + 1, LAn);
    __builtin_amdgcn_s_barrier();
    asm volatile("s_waitcnt lgkmcnt(0)" ::: "memory");
    __builtin_amdgcn_sched_barrier(0);
    __builtin_amdgcn_s_setprio(1);
#pragma unroll
    for (int m = 0; m < 2; ++m)
#pragma unroll
      for (int n = 0; n < 4; ++n) {
        acc[m][n] = __builtin_amdgcn_mfma_f32_16x16x32_bf16(af[m][0], bfr[n][0], acc[m][n], 0, 0, 0);
        acc[m][n] = __builtin_amdgcn_mfma_f32_16x16x32_bf16(af[m][1], bfr[n][1], acc[m][n], 0, 0, 0);
      }
    __builtin_amdgcn_s_setprio(0);
    __builtin_amdgcn_s_barrier();  // closes all waves' B reads of tile u

    // ---- phase 2: A m2,m3; stage B(u+1) into the (now-closed) B buffer ----
    af[0][0] = ldf(LA + aB + 2048 + sw0); af[0][1] = ldf(LA + aB + 2048 + sw1);
    af[1][0] = ldf(LA + aB + 3072 + sw0); af[1][1] = ldf(LA + aB + 3072 + sw1);
    if (st) stageB(u + 1);
    __builtin_amdgcn_s_barrier();
    asm volatile("s_waitcnt lgkmcnt(0)" ::: "memory");
    __builtin_amdgcn_sched_barrier(0);
    __builtin_amdgcn_s_setprio(1);
#pragma unroll
    for (int m = 0; m < 2; ++m)
#pragma unroll
      for (int n = 0; n < 4; ++n) {
        acc[2 + m][n] = __builtin_amdgcn_mfma_f32_16x16x32_bf16(af[m][0], bfr[n][0], acc[2 + m][n], 0, 0, 0);
        acc[2 + m][n] = __builtin_amdgcn_mfma_f32_16x16x32_bf16(af[m][1], bfr[n][1], acc[2 + m][n], 0, 0, 0);
      }
    __builtin_amdgcn_s_setprio(0);
    asm volatile("s_waitcnt vmcnt(0)" ::: "memory");  // staged A(u+1)+B(u+1) landed
    __builtin_amdgcn_s_barrier();
  }

  // epilogue: C write
#pragma unroll
  for (int m = 0; m < 4; ++m)
#pragma unroll
    for (int n = 0; n < 4; ++n)
#pragma unroll
      for (int j = 0; j < 4; ++j) {
        size_t r = row0 + wm * 64 + m * 16 + g4 * 4 + j;
        size_t c = col0 + wn * 64 + n * 16 + ro;
        if (OUT_F32)
          reinterpret_cast<float*>(Cp)[r * N + c] = acc[m][n][j];
        else
          reinterpret_cast<u16*>(Cp)[r * N + c] = f2bf(acc[m][n][j]);
      }
}

// ---------------- window attention ----------------
// grid: b*512 + w*8 + h  (2048 blocks), 512 threads (8 waves, 32 q-rows each).
// K in LDS via global_load_lds with pre-swizzled source (32KB); V transposed in
// LDS, XOR-swizzled (32KB); P per-wave quarter-split, XOR-swizzled (16KB).
// Total exactly 80KB -> 2 blocks/CU.
__global__ __launch_bounds__(512, 4) void attn_kernel(const u16* __restrict__ qp,
                                                      const u16* __restrict__ kvp,
                                                      u16* __restrict__ o) {
  __shared__ __align__(16) u16 Kl[256 * 64];
  __shared__ __align__(16) u16 Vt[64 * 256];
  __shared__ __align__(16) u16 Pl[8 * 1024];
  const int bid = blockIdx.x;
  const int h = bid & 7, w = (bid >> 3) & 63, b = bid >> 9;
  const int w1 = w >> 3, w2 = w & 7;
  const int tid = threadIdx.x, lane = tid & 63, wv = tid >> 6;

  auto lrow = [&](int t) { return (w1 * 16 + (t >> 4)) * 128 + w2 * 16 + (t & 15); };

  // stage K: 2048 16B chunks; LDS dest linear; global source pre-swizzled g^(r&7).
#pragma unroll
  for (int p = 0; p < 4; ++p) {
    int ci = tid + p * 512;
    int r = ci >> 3, g = (ci & 7) ^ (r & 7);
    gl_lds16(kvp + ((size_t)(b * LL + lrow(r))) * 1024 + h * 64 + g * 8, Kl + ci * 8);
  }
  // stage V transposed, swizzled: (d, tk) at phys d*256 + ((tk>>3)^(d&7))*8 + (tk&7)
  {
    const int tk = tid >> 1, half = tid & 1;
    const size_t base = ((size_t)(b * LL + lrow(tk))) * 1024 + 512 + h * 64 + half * 32;
#pragma unroll
    for (int c = 0; c < 4; ++c) {
      u16x8 vx = *reinterpret_cast<const u16x8*>(kvp + base + c * 8);
#pragma unroll
      for (int e = 0; e < 8; ++e) {
        int d = half * 32 + c * 8 + e;
        Vt[d * 256 + (((tk >> 3) ^ (d & 7)) * 8) + (tk & 7)] = vx[e];
      }
    }
  }
  __syncthreads();

  const int ro = lane & 15;       // low nibble
  const int g4 = lane >> 4;       // lane group 0..3
  const float scale = 0.125f;     // hd^-0.5, hd=64
  const int swA = (g4 ^ (ro & 7)) * 8;
  const int swB = ((g4 + 4) ^ (ro & 7)) * 8;
  u16* PW = Pl + wv * 1024;

  auto ldf = [&](const u16* p) { return *reinterpret_cast<const bf16x8*>(p); };

#pragma unroll
  for (int rt = 0; rt < 2; ++rt) {
    // Q fragments for this 16-row tile, direct from global
    const int tq = 32 * wv + 16 * rt + ro;
    const size_t qbase = ((size_t)(b * LL + lrow(tq))) * 512 + h * 64 + g4 * 8;
    const bf16x8 qf0 = *reinterpret_cast<const bf16x8*>(qp + qbase);
    const bf16x8 qf1 = *reinterpret_cast<const bf16x8*>(qp + qbase + 32);

    // S = Q K^T : 16 q-rows x 256 keys; K frags from swizzled LDS
    f32x4 sa[16] = {};
    __builtin_amdgcn_s_setprio(1);
#pragma unroll
    for (int ct = 0; ct < 16; ++ct) {
      bf16x8 kf0 = ldf(Kl + (16 * ct + ro) * 64 + swA);
      bf16x8 kf1 = ldf(Kl + (16 * ct + ro) * 64 + swB);
      sa[ct] = __builtin_amdgcn_mfma_f32_16x16x32_bf16(qf0, kf0, sa[ct], 0, 0, 0);
      sa[ct] = __builtin_amdgcn_mfma_f32_16x16x32_bf16(qf1, kf1, sa[ct], 0, 0, 0);
    }
    __builtin_amdgcn_s_setprio(0);

    // softmax per q-row (row = g4*4 + j, key = 16*ct + ro)
#pragma unroll
    for (int j = 0; j < 4; ++j) {
      float m = -1e30f;
#pragma unroll
      for (int ct = 0; ct < 16; ++ct) m = fmaxf(m, sa[ct][j]);
      m = fmaxf(m, __shfl_xor(m, 1));
      m = fmaxf(m, __shfl_xor(m, 2));
      m = fmaxf(m, __shfl_xor(m, 4));
      m = fmaxf(m, __shfl_xor(m, 8));
      m *= scale;
      float s = 0.f;
#pragma unroll
      for (int ct = 0; ct < 16; ++ct) {
        float p = __expf(sa[ct][j] * scale - m);
        sa[ct][j] = p;
        s += p;
      }
      s += __shfl_xor(s, 1);
      s += __shfl_xor(s, 2);
      s += __shfl_xor(s, 4);
      s += __shfl_xor(s, 8);
      float inv = 1.f / s;
#pragma unroll
      for (int ct = 0; ct < 16; ++ct) sa[ct][j] *= inv;
    }

    // O = P V in four key-quarters through the per-wave swizzled LDS P tile.
    f32x4 oacc[4] = {};
#pragma unroll
    for (int kh = 0; kh < 4; ++kh) {
#pragma unroll
      for (int c = 0; c < 4; ++c)
#pragma unroll
        for (int j = 0; j < 4; ++j) {
          int rq = g4 * 4 + j;
          PW[rq * 64 + (((2 * c + (ro >> 3)) ^ (rq & 7)) * 8) + (ro & 7)] =
              f2bf(sa[kh * 4 + c][j]);
        }
      __builtin_amdgcn_s_setprio(1);
#pragma unroll
      for (int ks = 0; ks < 2; ++ks) {
        bf16x8 pf = ldf(PW + ro * 64 + (((ks * 4 + g4) ^ (ro & 7)) * 8));
        const int kkg = kh * 2 + ks;
#pragma unroll
        for (int cd = 0; cd < 4; ++cd) {
          bf16x8 vf = ldf(Vt + (16 * cd + ro) * 256 + (((kkg * 4 + g4) ^ (ro & 7)) * 8));
          oacc[cd] = __builtin_amdgcn_mfma_f32_16x16x32_bf16(pf, vf, oacc[cd], 0, 0, 0);
        }
      }
      __builtin_amdgcn_s_setprio(0);
    }

    // write out this 16-row tile
#pragma unroll
    for (int cd = 0; cd < 4; ++cd)
#pragma unroll
      for (int j = 0; j < 4; ++j) {
        int t = 32 * wv + 16 * rt + g4 * 4 + j;
        int d = 16 * cd + ro;
        o[((size_t)(b * LL + lrow(t))) * 512 + h * 64 + d] = f2bf(oacc[cd][j]);
      }
  }
}

// ---------------- launch ----------------
extern "C" void kernel_launch(void* const* d_in, const int* in_sizes, int n_in,
                              void* d_out, int out_size, void* d_ws, size_t ws_size,
                              hipStream_t stream) {
  const float* q = (const float*)d_in[0];
  const float* kv = (const float*)d_in[1];
  const float* Wq = (const float*)d_in[2];
  const float* Wkv = (const float*)d_in[3];
  const float* Wfc = (const float*)d_in[4];
  float* out = (float*)d_out;
  char* ws = (char*)d_ws;

  // workspace layout (bytes)
  u16* q_bf  = (u16*)(ws + 0);            // 67108864  (also reused as o_buf)
  u16* kv_bf = (u16*)(ws + 67108864);     // 67108864
  u16* qp    = (u16*)(ws + 134217728);    // 67108864
  u16* kvp   = (u16*)(ws + 201326592);    // 134217728
  u16* Wq_t  = (u16*)(ws + 335544320);    // 524288
  u16* Wkv_t = (u16*)(ws + 336068608);    // 1048576
  u16* Wfc_t = (u16*)(ws + 337117184);    // 524288
  u16* o_buf = q_bf;                      // q_bf dead after GEMM1

  prep_kernel<<<4352, 256, 0, stream>>>(q, kv, Wq, Wkv, Wfc, q_bf, kv_bf, Wq_t, Wkv_t, Wfc_t);

  gemm128<false><<<2048, 256, 0, stream>>>(q_bf, Wq_t, qp, CC, 2);
  gemm128<false><<<4096, 256, 0, stream>>>(kv_bf, Wkv_t, kvp, 2 * CC, 3);

  attn_kernel<<<BB * 64 * 8, 512, 0, stream>>>(qp, kvp, o_buf);

  gemm128<true><<<2048, 256, 0, stream>>>(o_buf, Wfc_t, out, CC, 2);
}